// Round 8
// baseline (284.030 us; speedup 1.0000x reference)
//
#include <hip/hip_runtime.h>

#define BB 4
#define LL 2048
#define DD 1024
#define HH 16
#define HD 64

typedef __attribute__((ext_vector_type(8))) short s16x8;
typedef __attribute__((ext_vector_type(4))) short s16x4;
typedef __attribute__((ext_vector_type(4))) float f32x4;

#define SCALE_LOG2E 0.18033688011112042f  // 0.125 * log2(e), folded into Q

__device__ __forceinline__ short f2bf(float f) {
  union { float f; unsigned u; } c;
  c.f = f;
  return (short)((c.u + 0x7fffu + ((c.u >> 16) & 1u)) >> 16);  // RNE
}

// async global -> LDS, 16B per lane. LDS dest = wave-uniform base + lane*16.
__device__ __forceinline__ void cp16(const void* g, void* l) {
  __builtin_amdgcn_global_load_lds(
      (const __attribute__((address_space(1))) void*)g,
      (__attribute__((address_space(3))) void*)l, 16, 0, 0);
}

// ---------------- fused fp32 -> bf16 convert (x, W_qkv, W_out) -------------
// Outputs land contiguously at d_ws start, so one flat index serves all three.
__global__ __launch_bounds__(256) void f2b3_kernel(const float* __restrict__ x,
                                                   const float* __restrict__ w1,
                                                   const float* __restrict__ w2,
                                                   short* __restrict__ out) {
  const int i = blockIdx.x * 256 + threadIdx.x;  // 0..3145727 float4 groups
  const float* src;
  int off;
  if (i < 2097152) { src = x; off = i; }
  else if (i < 2883584) { src = w1; off = i - 2097152; }
  else { src = w2; off = i - 2883584; }
  float4 v = ((const float4*)src)[off];
  s16x4 o;
  o[0] = f2bf(v.x);
  o[1] = f2bf(v.y);
  o[2] = f2bf(v.z);
  o[3] = f2bf(v.w);
  ((s16x4*)out)[i] = o;
}

// ---------------- GEMM: C[M,N] = A[M,K] * B[N,K]^T (bf16 in, MFMA) ----------
// Double-buffered LDS, one barrier/iter. Orientation per block:
//  - MODE 0, n0<2048 (Q/K out) and MODE 1: TRANSPOSED tiles (mfma(bf,af)) so
//    each lane holds 4 consecutive output features -> 16 vector stores.
//  - MODE 0, n0>=2048 (V^T out): normal tiles; r packs 4 consecutive l -> b64.
// MODE 0: Q pre-scaled by SCALE_LOG2E; K [B,H,L,HD]; V^T [B,H,HD,L].
template <int MODE>
__global__ __launch_bounds__(256) void gemm_bt(const short* __restrict__ A,
                                               const short* __restrict__ Bm,
                                               int K, int N,
                                               short* __restrict__ qo,
                                               short* __restrict__ ko,
                                               short* __restrict__ vo,
                                               float* __restrict__ fo) {
  __shared__ __align__(16) short As[2][128 * 32];
  __shared__ __align__(16) short Bs[2][128 * 32];
  const int tid = threadIdx.x;
  const int m0 = blockIdx.y * 128, n0 = blockIdx.x * 128;
  const int wave = tid >> 6, lane = tid & 63;
  const int quad = lane >> 4, c16 = lane & 15;
  const int wr = (wave >> 1) * 64, wc = (wave & 1) * 64;
  const bool swapped = (MODE == 1) || (n0 < 2048);

  f32x4 zero = {0.f, 0.f, 0.f, 0.f};
  f32x4 acc[4][4];
#pragma unroll
  for (int i = 0; i < 4; i++)
#pragma unroll
    for (int j = 0; j < 4; j++) acc[i][j] = zero;

  const int row1 = tid >> 2, seg = (tid & 3) * 8;  // 64 rows x 4 16B-segments
  const short* Ag = A + (size_t)(m0 + row1) * K + seg;
  const short* Bg = Bm + (size_t)(n0 + row1) * K + seg;

  auto stage = [&](int k0, int bi) {
    cp16(Ag + k0, As[bi] + wave * 512);
    cp16(Ag + (size_t)64 * K + k0, As[bi] + 2048 + wave * 512);
    cp16(Bg + k0, Bs[bi] + wave * 512);
    cp16(Bg + (size_t)64 * K + k0, Bs[bi] + 2048 + wave * 512);
  };

  stage(0, 0);
  __syncthreads();
  const int T = K >> 5;
  for (int t = 0; t < T; t++) {
    if (t + 1 < T) stage((t + 1) * 32, (t + 1) & 1);
    const short* Asb = As[t & 1];
    const short* Bsb = Bs[t & 1];
    s16x8 af[4], bf[4];
#pragma unroll
    for (int i = 0; i < 4; i++)
      af[i] = *(const s16x8*)&Asb[(wr + i * 16 + c16) * 32 + quad * 8];
#pragma unroll
    for (int j = 0; j < 4; j++)
      bf[j] = *(const s16x8*)&Bsb[(wc + j * 16 + c16) * 32 + quad * 8];
    if (swapped) {
#pragma unroll
      for (int i = 0; i < 4; i++)
#pragma unroll
        for (int j = 0; j < 4; j++)
          acc[i][j] = __builtin_amdgcn_mfma_f32_16x16x32_bf16(bf[j], af[i], acc[i][j], 0, 0, 0);
    } else {
#pragma unroll
      for (int i = 0; i < 4; i++)
#pragma unroll
        for (int j = 0; j < 4; j++)
          acc[i][j] = __builtin_amdgcn_mfma_f32_16x16x32_bf16(af[i], bf[j], acc[i][j], 0, 0, 0);
    }
    __syncthreads();  // readers done with buf t; drains t+1 staging
  }

  if (MODE == 0) {
    if (n0 < 2048) {
      // Q/K, transposed: lane owns query gm=..+c16, features gnb..gnb+3
#pragma unroll
      for (int j = 0; j < 4; j++) {
        const int gnb = n0 + wc + j * 16 + quad * 4;
        const int which = gnb >> 10;
        const int h = (gnb >> 6) & 15;
        const int hd = gnb & 63;
        short* dst = which == 0 ? qo : ko;
        const float sc = which == 0 ? SCALE_LOG2E : 1.0f;
#pragma unroll
        for (int i = 0; i < 4; i++) {
          const int gm = m0 + wr + i * 16 + c16;
          const int b = gm >> 11, l = gm & 2047;
          s16x4 v;
#pragma unroll
          for (int r = 0; r < 4; r++) v[r] = f2bf(acc[i][j][r] * sc);
          *(s16x4*)&dst[((size_t)((b << 4) + h) * LL + l) * HD + hd] = v;
        }
      }
    } else {
      // V^T, normal: lane owns feature gn, queries gmb..gmb+3 (consecutive l)
#pragma unroll
      for (int j = 0; j < 4; j++) {
        const int gn = n0 + wc + j * 16 + c16;
        const int h = (gn >> 6) & 15;
        const int hd = gn & 63;
#pragma unroll
        for (int i = 0; i < 4; i++) {
          const int gmb = m0 + wr + i * 16 + quad * 4;
          const int b = gmb >> 11, l = gmb & 2047;
          s16x4 v;
#pragma unroll
          for (int r = 0; r < 4; r++) v[r] = f2bf(acc[i][j][r]);
          *(s16x4*)&vo[((size_t)((b << 4) + h) * HD + hd) * LL + l] = v;
        }
      }
    }
  } else {
    // fp32 out, transposed: lane owns row gm, 4 consecutive cols -> b128
#pragma unroll
    for (int i = 0; i < 4; i++) {
      const int gm = m0 + wr + i * 16 + c16;
#pragma unroll
      for (int j = 0; j < 4; j++) {
        const int gn = n0 + wc + j * 16 + quad * 4;
        *(f32x4*)&fo[(size_t)gm * N + gn] = acc[i][j];
      }
    }
  }
}

// ---------------- flash attention: paired q-blocks, 128-key tiles ----------
// Causal load balance: block pi processes q-block (15-pi) then q-block pi —
// exactly 17 tile-rounds per block, grid 8x64 = 512 blocks = 2/CU, every CU
// busy to the end. 128-key dbuf tiles (64 KB LDS). S^T = K*Q^T; P^T in
// registers (x16 B-operand); QK->softmax->PV fused per 16-key j-block.
// Q pre-scaled; p = 2^s (exact after p/l norm); denom via ones-A MFMA.
__global__ __launch_bounds__(256) void attn_kernel(const short* __restrict__ Qb,
                                                   const short* __restrict__ Kb,
                                                   const short* __restrict__ Vtb,
                                                   short* __restrict__ Cb) {
  const int pi = blockIdx.x;  // 0..7
  const int bh = blockIdx.y;  // 0..63
  const int tid = threadIdx.x;
  const int wave = tid >> 6, lane = tid & 63;
  const int quad = lane >> 4, c16 = lane & 15;
  const int sw = c16 & 7;  // K-read swizzle term
  const size_t base = (size_t)bh * LL * HD;
  const short* Q = Qb + base;
  const short* K = Kb + base;
  const short* Vt = Vtb + base;  // [HD][LL]

  __shared__ __align__(16) short Ks[2][128 * 64];  // [key][hd], 3-bit swizzle
  __shared__ __align__(16) short Vs[2][64 * 128];  // [hd][key], 4-bit swizzle

  const f32x4 zero = {0.f, 0.f, 0.f, 0.f};
  const s16x4 ones = {(short)0x3F80, (short)0x3F80, (short)0x3F80, (short)0x3F80};

  // staging: K 4 issues (32 rows x 128B each), V 4 issues (16 rows x 256B)
  const int k_r = lane >> 3, k_c = lane & 7;    // K: 8-row slab, 8 granules
  const int v_r = lane >> 4, v_c = lane & 15;   // V: 4-row slab, 16 granules
  auto stage = [&](int kb, int bi) {
#pragma unroll
    for (int i = 0; i < 4; i++) {
      const int gk = i * 32 + wave * 8 + k_r;
      cp16(K + (size_t)(kb + gk) * HD + ((k_c ^ (gk & 7)) * 8),
           &Ks[bi][i * 2048 + wave * 512]);
      const int gv = i * 16 + wave * 4 + v_r;
      cp16(Vt + (size_t)gv * LL + kb + ((v_c ^ (gv & 15)) * 8),
           &Vs[bi][i * 2048 + wave * 512]);
    }
  };

  // pack 4 f32 -> 4 truncated bf16 via 2 x v_perm_b32
  auto pack4 = [&](const float* p) {
    union { float f; unsigned u; } a0, a1, a2, a3;
    a0.f = p[0]; a1.f = p[1]; a2.f = p[2]; a3.f = p[3];
    union { s16x4 v; unsigned u[2]; } r;
    r.u[0] = __builtin_amdgcn_perm(a1.u, a0.u, 0x07060302u);
    r.u[1] = __builtin_amdgcn_perm(a3.u, a2.u, 0x07060302u);
    return r.v;
  };

  for (int phase = 0; phase < 2; phase++) {
    const int qg = phase == 0 ? (15 - pi) : pi;  // heavy first
    const int qw = qg * 128 + wave * 32;         // this wave's 32 queries
    const int tiles = qg + 1;                    // 128-key tiles

    s16x8 qf[2][2];
#pragma unroll
    for (int h = 0; h < 2; h++)
#pragma unroll
      for (int s = 0; s < 2; s++)
        qf[h][s] = *(const s16x8*)(Q + (size_t)(qw + h * 16 + c16) * HD + s * 32 + quad * 8);

    f32x4 o[2][4];
#pragma unroll
    for (int h = 0; h < 2; h++)
#pragma unroll
      for (int j = 0; j < 4; j++) o[h][j] = zero;
    f32x4 ol[2] = {zero, zero};

    stage(0, 0);
    __syncthreads();  // drain tile 0 (also isolates phase 0's last readers)

    for (int t = 0; t < tiles; t++) {
      const int kb = t * 128;
      if (t + 1 < tiles) stage(kb + 128, (t + 1) & 1);
      const short* Kt = &Ks[t & 1][0];
      const short* Vv = &Vs[t & 1][0];

      // causal bounds (wave-uniform): half h covers queries qw+h*16..+15
      const int D0 = qw - kb, D1 = D0 + 16;
      const int jm0 = D0 < 0 ? 0 : min((D0 >> 4) + 1, 8);
      const int jm1 = D1 < 0 ? 0 : min((D1 >> 4) + 1, 8);
      const int jb0 = D0 >> 4, jb1 = D1 >> 4;

#pragma unroll
      for (int j = 0; j < 8; j++) {
        if (j >= jm1) continue;  // wave-uniform skip
        s16x8 kf0 = *(const s16x8*)&Kt[(j * 16 + c16) * 64 + ((quad ^ sw) * 8)];
        s16x8 kf1 = *(const s16x8*)&Kt[(j * 16 + c16) * 64 + (((4 + quad) ^ sw) * 8)];
        s16x4 va[4];
#pragma unroll
        for (int j4 = 0; j4 < 4; j4++)
          va[j4] = *(const s16x4*)&Vv[(j4 * 16 + c16) * 128 +
                                      (((2 * j + (quad >> 1)) ^ c16) * 8) + (quad & 1) * 4];
        // half 1
        {
          f32x4 s = __builtin_amdgcn_mfma_f32_16x16x32_bf16(kf0, qf[1][0], zero, 0, 0, 0);
          s = __builtin_amdgcn_mfma_f32_16x16x32_bf16(kf1, qf[1][1], s, 0, 0, 0);
          float p[4];
#pragma unroll
          for (int r = 0; r < 4; r++) p[r] = __builtin_amdgcn_exp2f(s[r]);
          if (j == jb1) {
            const int thr = c16 + D1 - j * 16 - quad * 4;
#pragma unroll
            for (int r = 0; r < 4; r++)
              if (r > thr) p[r] = 0.f;
          }
          s16x4 pb = pack4(p);
          ol[1] = __builtin_amdgcn_mfma_f32_16x16x16bf16_1k(ones, pb, ol[1], 0, 0, 0);
#pragma unroll
          for (int j4 = 0; j4 < 4; j4++)
            o[1][j4] = __builtin_amdgcn_mfma_f32_16x16x16bf16_1k(va[j4], pb, o[1][j4], 0, 0, 0);
        }
        // half 0
        if (j < jm0) {
          f32x4 s = __builtin_amdgcn_mfma_f32_16x16x32_bf16(kf0, qf[0][0], zero, 0, 0, 0);
          s = __builtin_amdgcn_mfma_f32_16x16x32_bf16(kf1, qf[0][1], s, 0, 0, 0);
          float p[4];
#pragma unroll
          for (int r = 0; r < 4; r++) p[r] = __builtin_amdgcn_exp2f(s[r]);
          if (j == jb0) {
            const int thr = c16 + D0 - j * 16 - quad * 4;
#pragma unroll
            for (int r = 0; r < 4; r++)
              if (r > thr) p[r] = 0.f;
          }
          s16x4 pb = pack4(p);
          ol[0] = __builtin_amdgcn_mfma_f32_16x16x16bf16_1k(ones, pb, ol[0], 0, 0, 0);
#pragma unroll
          for (int j4 = 0; j4 < 4; j4++)
            o[0][j4] = __builtin_amdgcn_mfma_f32_16x16x16bf16_1k(va[j4], pb, o[0][j4], 0, 0, 0);
        }
      }

      __syncthreads();  // readers done with buf t; drains t+1 staging
    }

    const int b = bh >> 4, h2 = bh & 15;
#pragma unroll
    for (int h = 0; h < 2; h++) {
      const float inv = 1.0f / ol[h][0];
      const int q = qw + h * 16 + c16;
#pragma unroll
      for (int j4 = 0; j4 < 4; j4++) {
        s16x4 ov;
#pragma unroll
        for (int r = 0; r < 4; r++) ov[r] = f2bf(o[h][j4][r] * inv);
        *(s16x4*)&Cb[(size_t)(b * LL + q) * DD + h2 * HD + j4 * 16 + quad * 4] = ov;
      }
    }
  }
}

// ---------------- launch ----------------
extern "C" void kernel_launch(void* const* d_in, const int* in_sizes, int n_in,
                              void* d_out, int out_size, void* d_ws, size_t ws_size,
                              hipStream_t stream) {
  const float* x = (const float*)d_in[0];
  const float* wqkv = (const float*)d_in[1];
  const float* wout = (const float*)d_in[2];
  float* out = (float*)d_out;

  const size_t NX = (size_t)BB * LL * DD;  // 8388608
  short* xb = (short*)d_ws;
  short* wqkvb = xb + NX;
  short* woutb = wqkvb + (size_t)3 * DD * DD;
  short* qb = woutb + (size_t)DD * DD;
  short* kb = qb + NX;
  short* vb = kb + NX;   // V transposed: [B,H,HD,L]
  short* cb = vb + NX;
  // total: 92,274,688 bytes of d_ws

  f2b3_kernel<<<dim3(12288), 256, 0, stream>>>(x, wqkv, wout, xb);

  gemm_bt<0><<<dim3(3 * DD / 128, BB * LL / 128), 256, 0, stream>>>(
      xb, wqkvb, DD, 3 * DD, qb, kb, vb, nullptr);
  attn_kernel<<<dim3(8, BB * HH), 256, 0, stream>>>(qb, kb, vb, cb);
  gemm_bt<1><<<dim3(DD / 128, BB * LL / 128), 256, 0, stream>>>(
      cb, woutb, DD, DD, nullptr, nullptr, nullptr, out);
}